// Round 5
// baseline (2834.684 us; speedup 1.0000x reference)
//
#include <hip/hip_runtime.h>

#define B 8
#define N 16384
#define S 2048
#define NS 32
#define CIN 16
#define NCELL 512

// ---------------- DPP wave-64 reductions (all lanes active) ----------------
template<int CTRL>
__device__ __forceinline__ float dpp_fmax(float x) {
    int t = __builtin_amdgcn_update_dpp(0, __float_as_int(x), CTRL, 0xF, 0xF, true);
    return fmaxf(x, __int_as_float(t));
}
template<int CTRL>
__device__ __forceinline__ unsigned dpp_umax(unsigned x) {
    unsigned t = (unsigned)__builtin_amdgcn_update_dpp(0, (int)x, CTRL, 0xF, 0xF, true);
    return x > t ? x : t;
}
__device__ __forceinline__ float wave_fmax(float x) {
    x = dpp_fmax<0xB1>(x);      // quad_perm xor1
    x = dpp_fmax<0x4E>(x);      // quad_perm xor2
    x = dpp_fmax<0x114>(x);     // row_shr:4
    x = dpp_fmax<0x118>(x);     // row_shr:8
    x = dpp_fmax<0x142>(x);     // row_bcast:15
    x = dpp_fmax<0x143>(x);     // row_bcast:31
    return __int_as_float(__builtin_amdgcn_readlane(__float_as_int(x), 63));
}
__device__ __forceinline__ unsigned wave_umax(unsigned x) {
    x = dpp_umax<0xB1>(x);
    x = dpp_umax<0x4E>(x);
    x = dpp_umax<0x114>(x);
    x = dpp_umax<0x118>(x);
    x = dpp_umax<0x142>(x);
    x = dpp_umax<0x143>(x);
    return (unsigned)__builtin_amdgcn_readlane((int)x, 63);
}

__device__ __forceinline__ int expand3(int v) {
    return (v & 1) | ((v & 2) << 2) | ((v & 4) << 4);
}

// ---------------- bucket sort: morton-cell order, SoA output ----------------
__global__ __launch_bounds__(1024) void bucket_kernel(const float* __restrict__ xyz,
                                                      float* __restrict__ Xp,
                                                      float* __restrict__ Yp,
                                                      float* __restrict__ Zp,
                                                      int* __restrict__ Ip) {
    const int b = blockIdx.x;
    const int t = threadIdx.x;
    const float* xb = xyz + (size_t)b * N * 3;

    __shared__ int hist[NCELL], pA[NCELL], pB[NCELL], run[NCELL];
    if (t < NCELL) { hist[t] = 0; run[t] = 0; }
    __syncthreads();

    int cell[16];
    float xs[16], ys[16], zs[16];
#pragma unroll
    for (int k = 0; k < 16; ++k) {
        const int n = t + (k << 10);
        const float x = xb[3 * n + 0];
        const float y = xb[3 * n + 1];
        const float z = xb[3 * n + 2];
        int cx = min(7, max(0, (int)(x * 8.0f)));
        int cy = min(7, max(0, (int)(y * 8.0f)));
        int cz = min(7, max(0, (int)(z * 8.0f)));
        const int c = expand3(cx) | (expand3(cy) << 1) | (expand3(cz) << 2);
        cell[k] = c; xs[k] = x; ys[k] = y; zs[k] = z;
        atomicAdd(&hist[c], 1);
    }
    __syncthreads();

    int* cur = pA; int* nxt = pB;
    if (t < NCELL) cur[t] = hist[t];
    __syncthreads();
    for (int off = 1; off < NCELL; off <<= 1) {
        if (t < NCELL) nxt[t] = cur[t] + ((t >= off) ? cur[t - off] : 0);
        __syncthreads();
        int* tmp = cur; cur = nxt; nxt = tmp;
    }
    if (t < NCELL) nxt[t] = cur[t] - hist[t];
    __syncthreads();
    const int* base = nxt;

#pragma unroll
    for (int k = 0; k < 16; ++k) {
        const int c = cell[k];
        const int pos = base[c] + atomicAdd(&run[c], 1);
        const size_t o = (size_t)b * N + pos;
        Xp[o] = xs[k]; Yp[o] = ys[k]; Zp[o] = zs[k];
        Ip[o] = t + (k << 10);
    }
}

// ---------------- FPS: bbox prune + DPP reduce + slot/shfl block reduce ----------------
__global__ __launch_bounds__(1024) __attribute__((amdgpu_waves_per_eu(4, 4)))
void fps_prune_kernel(const float* __restrict__ xyz,
                      const float* __restrict__ Xp,
                      const float* __restrict__ Yp,
                      const float* __restrict__ Zp,
                      const int* __restrict__ Ip,
                      float* __restrict__ new_xyz) {
#pragma clang fp contract(off)
    const int b = blockIdx.x;
    const int t = threadIdx.x;
    const float* xb = xyz + (size_t)b * N * 3;
    const int lane = t & 63;
    const int w = t >> 6;
    const size_t base = (size_t)b * N + ((size_t)t << 4);   // 16 consecutive sorted pts

    float px[16], py[16], pz[16], md[16];
    int ip[16];
#pragma unroll
    for (int k = 0; k < 16; ++k) {
        px[k] = Xp[base + k];
        py[k] = Yp[base + k];
        pz[k] = Zp[base + k];
        ip[k] = Ip[base + k];
        md[k] = 1e10f;
    }
    // pin: forbids rematerialized global reloads
#pragma unroll
    for (int k = 0; k < 16; ++k) {
        asm volatile("" : "+v"(px[k]), "+v"(py[k]), "+v"(pz[k]), "+v"(ip[k]));
    }

    // per-thread bbox (tight: points are Morton-adjacent)
    float lox = px[0], hix = px[0], loy = py[0], hiy = py[0], loz = pz[0], hiz = pz[0];
#pragma unroll
    for (int k = 1; k < 16; ++k) {
        lox = fminf(lox, px[k]); hix = fmaxf(hix, px[k]);
        loy = fminf(loy, py[k]); hiy = fmaxf(hiy, py[k]);
        loz = fminf(loz, pz[k]); hiz = fmaxf(hiz, pz[k]);
    }

    __shared__ unsigned long long sk[2][16];   // per-wave packed (ub<<32 | ~cand)
    int p = 0;

    float ub = 1e10f;
    int cand = ip[0];
    // initial centroid = original point 0 (broadcast L2 read, once)
    float cx = xb[0], cy = xb[1], cz = xb[2];

    for (int it = 0; it < S; ++it) {
        if (t == 0) {
            float* o = new_xyz + ((size_t)b * S + it) * 3;
            o[0] = cx; o[1] = cy; o[2] = cz;
        }
        // exact conservative skip: lb*(1-2e-5) > ub  =>  d_fp32 > md for all 16 pts
        const float ddx = fmaxf(0.0f, fmaxf(lox - cx, cx - hix));
        const float ddy = fmaxf(0.0f, fmaxf(loy - cy, cy - hiy));
        const float ddz = fmaxf(0.0f, fmaxf(loz - cz, cz - hiz));
        const float lb = (ddx * ddx + ddy * ddy) + ddz * ddz;

        if (!(lb * 0.99998f > ub)) {
            float nu = 0.0f;
#pragma unroll
            for (int k = 0; k < 16; ++k) {
                const float dx = __fsub_rn(px[k], cx);
                const float dy = __fsub_rn(py[k], cy);
                const float dz = __fsub_rn(pz[k], cz);
                const float d  = __fadd_rn(__fadd_rn(__fmul_rn(dx, dx), __fmul_rn(dy, dy)),
                                           __fmul_rn(dz, dz));
                const float m = fminf(md[k], d);
                md[k] = m;
                nu = fmaxf(nu, m);
            }
            int c = 0x7fffffff;
#pragma unroll
            for (int k = 0; k < 16; ++k) {
                if (md[k] == nu) c = min(c, ip[k]);
            }
            ub = nu; cand = c;
        }
        // wave reduce (DPP): max ub, then min orig idx among ties
        const float wmax = wave_fmax(ub);
        unsigned cn = (ub == wmax) ? ~(unsigned)cand : 0u;
        cn = wave_umax(cn);
        if (lane == 63) {
            sk[p][w] = ((unsigned long long)__float_as_uint(wmax) << 32)
                     | (unsigned long long)cn;
        }
        __syncthreads();
        // block reduce: 16 wave slots, 4-step butterfly (every thread redundantly)
        unsigned long long key = sk[p][lane & 15];
#pragma unroll
        for (int off = 8; off >= 1; off >>= 1) {
            const unsigned long long ko = __shfl_xor(key, off);
            key = (ko > key) ? ko : key;
        }
        const int far = (int)(~(unsigned)key);
        cx = xb[3 * far + 0];
        cy = xb[3 * far + 1];
        cz = xb[3 * far + 2];
        p ^= 1;
    }
}

// ---------------- fallback FPS (no workspace) ----------------
__global__ __launch_bounds__(1024) void fps_kernel(const float* __restrict__ xyz,
                                                   float* __restrict__ new_xyz) {
#pragma clang fp contract(off)
    const int b = blockIdx.x;
    const int t = threadIdx.x;
    const float* xb = xyz + (size_t)b * N * 3;

    float px[16], py[16], pz[16], md[16];
#pragma unroll
    for (int k = 0; k < 16; ++k) {
        const int n = t + (k << 10);
        px[k] = xb[3 * n + 0];
        py[k] = xb[3 * n + 1];
        pz[k] = xb[3 * n + 2];
        md[k] = 1e10f;
    }
    __shared__ float rv[2][16];
    __shared__ int slot[2];
    if (t == 0) { slot[0] = 0x7fffffff; slot[1] = 0x7fffffff; }
    __syncthreads();
    int far = 0, p = 0;
    const int lane = t & 63, w = t >> 6;
    for (int it = 0; it < S; ++it) {
        const float cx = xb[3 * far + 0], cy = xb[3 * far + 1], cz = xb[3 * far + 2];
        if (t == 0) {
            float* o = new_xyz + ((size_t)b * S + it) * 3;
            o[0] = cx; o[1] = cy; o[2] = cz;
        }
        float bestv = -1.0f;
#pragma unroll
        for (int k = 0; k < 16; ++k) {
            const float dx = __fsub_rn(px[k], cx);
            const float dy = __fsub_rn(py[k], cy);
            const float dz = __fsub_rn(pz[k], cz);
            const float d  = __fadd_rn(__fadd_rn(__fmul_rn(dx, dx), __fmul_rn(dy, dy)),
                                       __fmul_rn(dz, dz));
            const float m = fminf(md[k], d);
            md[k] = m;
            bestv = fmaxf(bestv, m);
        }
        float v = bestv;
#pragma unroll
        for (int off = 32; off >= 1; off >>= 1) v = fmaxf(v, __shfl_xor(v, off));
        if (lane == 0) rv[p][w] = v;
        __syncthreads();
        float u = rv[p][lane & 15];
#pragma unroll
        for (int off = 8; off >= 1; off >>= 1) u = fmaxf(u, __shfl_xor(u, off));
        if (t == 0) slot[p ^ 1] = 0x7fffffff;
        if (bestv == u) {
            int cnd2 = 0x7fffffff;
#pragma unroll
            for (int k = 0; k < 16; ++k)
                if (md[k] == u) cnd2 = min(cnd2, t + (k << 10));
            atomicMin(&slot[p], cnd2);
        }
        __syncthreads();
        far = slot[p];
        p ^= 1;
    }
}

// ---------------- ball query + group + MLP + maxpool: one wave per query ----------------
__global__ __launch_bounds__(64) void ball_mlp_kernel(
    const float* __restrict__ xyz,
    const float* __restrict__ feat,
    const float* __restrict__ W1, const float* __restrict__ b1,
    const float* __restrict__ W2, const float* __restrict__ b2,
    const float* __restrict__ W3, const float* __restrict__ b3,
    const float* __restrict__ new_xyz,
    float* __restrict__ out_feat) {
#pragma clang fp contract(off)
    const int q = blockIdx.x;          // b*S + s
    const int b = q >> 11;             // S = 2048
    const int lane = threadIdx.x;
    const float* xb = xyz + (size_t)b * N * 3;

    const double qx = (double)new_xyz[3 * q + 0];
    const double qy = (double)new_xyz[3 * q + 1];
    const double qz = (double)new_xyz[3 * q + 2];
    const double s2 = qx * qx + qy * qy + qz * qz;
    const double R2 = 0.1 * 0.1;

    __shared__ int idxbuf[NS];
    int found = 0;
    for (int bs = 0; bs < N; bs += 64) {
        const int n = bs + lane;
        const double x = (double)xb[3 * n + 0];
        const double y = (double)xb[3 * n + 1];
        const double z = (double)xb[3 * n + 2];
        const double n2 = x * x + y * y + z * z;
        const double dt = qx * x + qy * y + qz * z;
        const double d2 = (s2 + n2) - 2.0 * dt;
        const bool ok = (d2 <= R2);
        const unsigned long long msk = __ballot(ok);
        if (ok) {
            const int pos = found + (int)__popcll(msk & ((1ull << lane) - 1ull));
            if (pos < NS) idxbuf[pos] = n;
        }
        found += (int)__popcll(msk);
        if (found >= NS) break;
    }
    __syncthreads();
    if (lane == 0) {
        const int cnt = found < NS ? found : NS;
        const int first = (cnt > 0) ? idxbuf[0] : (N - 1);
        for (int j2 = cnt; j2 < NS; ++j2) idxbuf[j2] = first;
    }
    __syncthreads();

    const int j = lane & 31;           // neighbor
    const int h = lane >> 5;           // channel half
    const int nid = idxbuf[j];
    const float* fp = feat + ((size_t)b * N + nid) * CIN;
    float fv[CIN];
#pragma unroll
    for (int k = 0; k < CIN; ++k) fv[k] = fp[k];

    float h1[32];
#pragma unroll
    for (int c = 0; c < 32; ++c) {
        float a = b1[c];
#pragma unroll
        for (int k = 0; k < CIN; ++k) a = fmaf(fv[k], W1[(k << 5) + c], a);
        h1[c] = fmaxf(a, 0.0f);
    }
    float h2[32];
#pragma unroll
    for (int c = 0; c < 32; ++c) {
        float a = b2[c];
#pragma unroll
        for (int k = 0; k < 32; ++k) a = fmaf(h1[k], W2[(k << 5) + c], a);
        h2[c] = fmaxf(a, 0.0f);
    }
    const int cbase = h << 5;
    float mx[32];
#pragma unroll
    for (int c = 0; c < 32; ++c) {
        float a = b3[cbase + c];
#pragma unroll
        for (int k = 0; k < 32; ++k) a = fmaf(h2[k], W3[(k << 6) + cbase + c], a);
        mx[c] = a;
    }
#pragma unroll
    for (int off = 1; off <= 16; off <<= 1) {
#pragma unroll
        for (int c = 0; c < 32; ++c) mx[c] = fmaxf(mx[c], __shfl_xor(mx[c], off));
    }
    if (j == 0) {
        float* o = out_feat + (size_t)q * 64 + cbase;
#pragma unroll
        for (int c = 0; c < 32; ++c) o[c] = mx[c];
    }
}

extern "C" void kernel_launch(void* const* d_in, const int* in_sizes, int n_in,
                              void* d_out, int out_size, void* d_ws, size_t ws_size,
                              hipStream_t stream) {
    (void)in_sizes; (void)n_in; (void)out_size;
    const float* xyz  = (const float*)d_in[0];
    const float* feat = (const float*)d_in[1];
    const float* W1   = (const float*)d_in[2];
    const float* b1   = (const float*)d_in[3];
    const float* W2   = (const float*)d_in[4];
    const float* b2   = (const float*)d_in[5];
    const float* W3   = (const float*)d_in[6];
    const float* b3   = (const float*)d_in[7];

    float* out      = (float*)d_out;
    float* new_xyz  = out;                          // B*S*3 floats
    float* new_feat = out + (size_t)B * S * 3;      // B*S*64 floats

    const size_t need = (size_t)4 * B * N * sizeof(float);
    if (ws_size >= need) {
        float* Xp = (float*)d_ws;
        float* Yp = Xp + (size_t)B * N;
        float* Zp = Yp + (size_t)B * N;
        int*   Ip = (int*)(Zp + (size_t)B * N);
        bucket_kernel<<<B, 1024, 0, stream>>>(xyz, Xp, Yp, Zp, Ip);
        fps_prune_kernel<<<B, 1024, 0, stream>>>(xyz, Xp, Yp, Zp, Ip, new_xyz);
    } else {
        fps_kernel<<<B, 1024, 0, stream>>>(xyz, new_xyz);
    }
    ball_mlp_kernel<<<B * S, 64, 0, stream>>>(xyz, feat, W1, b1, W2, b2, W3, b3,
                                              new_xyz, new_feat);
}

// Round 6
// 2361.540 us; speedup vs baseline: 1.2004x; 1.2004x over previous
//
#include <hip/hip_runtime.h>

#define B 8
#define N 16384
#define S 2048
#define NS 32
#define CIN 16
#define NCELL 512

typedef float f32x2 __attribute__((ext_vector_type(2)));
typedef int   i32x2 __attribute__((ext_vector_type(2)));

// ---------------- DPP wave-64 reductions (all lanes active) ----------------
template<int CTRL>
__device__ __forceinline__ float dpp_fmax(float x) {
    int t = __builtin_amdgcn_update_dpp(0, __float_as_int(x), CTRL, 0xF, 0xF, true);
    return fmaxf(x, __int_as_float(t));
}
template<int CTRL>
__device__ __forceinline__ unsigned dpp_umax(unsigned x) {
    unsigned t = (unsigned)__builtin_amdgcn_update_dpp(0, (int)x, CTRL, 0xF, 0xF, true);
    return x > t ? x : t;
}
__device__ __forceinline__ float wave_fmax(float x) {
    x = dpp_fmax<0xB1>(x);      // quad_perm xor1
    x = dpp_fmax<0x4E>(x);      // quad_perm xor2
    x = dpp_fmax<0x114>(x);     // row_shr:4
    x = dpp_fmax<0x118>(x);     // row_shr:8
    x = dpp_fmax<0x142>(x);     // row_bcast:15
    x = dpp_fmax<0x143>(x);     // row_bcast:31
    return __int_as_float(__builtin_amdgcn_readlane(__float_as_int(x), 63));
}
__device__ __forceinline__ unsigned wave_umax(unsigned x) {
    x = dpp_umax<0xB1>(x);
    x = dpp_umax<0x4E>(x);
    x = dpp_umax<0x114>(x);
    x = dpp_umax<0x118>(x);
    x = dpp_umax<0x142>(x);
    x = dpp_umax<0x143>(x);
    return (unsigned)__builtin_amdgcn_readlane((int)x, 63);
}

__device__ __forceinline__ int expand3(int v) {
    return (v & 1) | ((v & 2) << 2) | ((v & 4) << 4);
}

// ---------------- bucket sort: morton-cell order, SoA output ----------------
__global__ __launch_bounds__(1024) void bucket_kernel(const float* __restrict__ xyz,
                                                      float* __restrict__ Xp,
                                                      float* __restrict__ Yp,
                                                      float* __restrict__ Zp,
                                                      int* __restrict__ Ip) {
    const int b = blockIdx.x;
    const int t = threadIdx.x;
    const float* xb = xyz + (size_t)b * N * 3;

    __shared__ int hist[NCELL], pA[NCELL], pB[NCELL], run[NCELL];
    if (t < NCELL) { hist[t] = 0; run[t] = 0; }
    __syncthreads();

    int cell[16];
    float xs[16], ys[16], zs[16];
#pragma unroll
    for (int k = 0; k < 16; ++k) {
        const int n = t + (k << 10);
        const float x = xb[3 * n + 0];
        const float y = xb[3 * n + 1];
        const float z = xb[3 * n + 2];
        int cx = min(7, max(0, (int)(x * 8.0f)));
        int cy = min(7, max(0, (int)(y * 8.0f)));
        int cz = min(7, max(0, (int)(z * 8.0f)));
        const int c = expand3(cx) | (expand3(cy) << 1) | (expand3(cz) << 2);
        cell[k] = c; xs[k] = x; ys[k] = y; zs[k] = z;
        atomicAdd(&hist[c], 1);
    }
    __syncthreads();

    int* cur = pA; int* nxt = pB;
    if (t < NCELL) cur[t] = hist[t];
    __syncthreads();
    for (int off = 1; off < NCELL; off <<= 1) {
        if (t < NCELL) nxt[t] = cur[t] + ((t >= off) ? cur[t - off] : 0);
        __syncthreads();
        int* tmp = cur; cur = nxt; nxt = tmp;
    }
    if (t < NCELL) nxt[t] = cur[t] - hist[t];
    __syncthreads();
    const int* base = nxt;

#pragma unroll
    for (int k = 0; k < 16; ++k) {
        const int c = cell[k];
        const int pos = base[c] + atomicAdd(&run[c], 1);
        const size_t o = (size_t)b * N + pos;
        Xp[o] = xs[k]; Yp[o] = ys[k]; Zp[o] = zs[k];
        Ip[o] = t + (k << 10);
    }
}

// ---------------- FPS: bbox prune + packed-f32 update + 3-slot atomic reduce ----------------
__global__ __launch_bounds__(1024, 1) void fps_prune_kernel(const float* __restrict__ xyz,
                                                            const float* __restrict__ Xp,
                                                            const float* __restrict__ Yp,
                                                            const float* __restrict__ Zp,
                                                            const int* __restrict__ Ip,
                                                            float* __restrict__ new_xyz) {
#pragma clang fp contract(off)
    const int b = blockIdx.x;
    const int t = threadIdx.x;
    const float* xb = xyz + (size_t)b * N * 3;
    const size_t base = (size_t)b * N + ((size_t)t << 4);   // 16 consecutive sorted pts

    f32x2 px[8], py[8], pz[8], md[8];
    i32x2 ip[8];
    {
        const f32x2* X2 = (const f32x2*)(Xp + base);
        const f32x2* Y2 = (const f32x2*)(Yp + base);
        const f32x2* Z2 = (const f32x2*)(Zp + base);
        const i32x2* I2 = (const i32x2*)(Ip + base);
#pragma unroll
        for (int j = 0; j < 8; ++j) {
            px[j] = X2[j]; py[j] = Y2[j]; pz[j] = Z2[j]; ip[j] = I2[j];
            md[j] = (f32x2){1e10f, 1e10f};
        }
    }

    // per-thread bbox (tight: points are Morton-adjacent)
    float lox = px[0].x, hix = px[0].x, loy = py[0].x, hiy = py[0].x,
          loz = pz[0].x, hiz = pz[0].x;
#pragma unroll
    for (int j = 0; j < 8; ++j) {
        lox = fminf(lox, fminf(px[j].x, px[j].y)); hix = fmaxf(hix, fmaxf(px[j].x, px[j].y));
        loy = fminf(loy, fminf(py[j].x, py[j].y)); hiy = fmaxf(hiy, fmaxf(py[j].x, py[j].y));
        loz = fminf(loz, fminf(pz[j].x, pz[j].y)); hiz = fmaxf(hiz, fmaxf(pz[j].x, pz[j].y));
    }

    __shared__ unsigned long long slot3[3];
    if (t == 0) { slot3[0] = 0ull; slot3[1] = 0ull; slot3[2] = 0ull; }
    __syncthreads();

    int p = 0;
    float ub = 1e10f;
    int cand = ip[0].x;
    unsigned long long wkey = 0ull;
    float cx = xb[0], cy = xb[1], cz = xb[2];   // initial centroid = original point 0

    for (int it = 0; it < S; ++it) {
        if (t == 0) {
            float* o = new_xyz + ((size_t)b * S + it) * 3;
            o[0] = cx; o[1] = cy; o[2] = cz;
        }
        // exact conservative skip: lb*(1-2e-5) > ub  =>  d_fp32 > md for all 16 pts
        const float ddx = fmaxf(0.0f, fmaxf(lox - cx, cx - hix));
        const float ddy = fmaxf(0.0f, fmaxf(loy - cy, cy - hiy));
        const float ddz = fmaxf(0.0f, fmaxf(loz - cz, cz - hiz));
        const float lb = (ddx * ddx + ddy * ddy) + ddz * ddz;
        const bool upd = !(lb * 0.99998f > ub);

        if (__any(upd)) {                 // wave-uniform: all 64 lanes active inside
            if (upd) {
                // pin point data into arch VGPRs at every update (defeats
                // remat/AGPR-shuttle: keeping resident is now the cheap plan)
                asm volatile("" : "+v"(px[0]), "+v"(px[1]), "+v"(px[2]), "+v"(px[3]),
                                  "+v"(px[4]), "+v"(px[5]), "+v"(px[6]), "+v"(px[7]));
                asm volatile("" : "+v"(py[0]), "+v"(py[1]), "+v"(py[2]), "+v"(py[3]),
                                  "+v"(py[4]), "+v"(py[5]), "+v"(py[6]), "+v"(py[7]));
                asm volatile("" : "+v"(pz[0]), "+v"(pz[1]), "+v"(pz[2]), "+v"(pz[3]),
                                  "+v"(pz[4]), "+v"(pz[5]), "+v"(pz[6]), "+v"(pz[7]));
                asm volatile("" : "+v"(ip[0]), "+v"(ip[1]), "+v"(ip[2]), "+v"(ip[3]),
                                  "+v"(ip[4]), "+v"(ip[5]), "+v"(ip[6]), "+v"(ip[7]));
                const f32x2 c2x = {cx, cx}, c2y = {cy, cy}, c2z = {cz, cz};
                float nu = 0.0f;
#pragma unroll
                for (int j = 0; j < 8; ++j) {
                    // identical rounding order to scalar version; packed v_pk_* ops
                    const f32x2 dx = px[j] - c2x;
                    const f32x2 dy = py[j] - c2y;
                    const f32x2 dz = pz[j] - c2z;
                    const f32x2 xx = dx * dx;
                    const f32x2 yy = dy * dy;
                    const f32x2 zz = dz * dz;
                    const f32x2 ss = xx + yy;
                    const f32x2 dd = ss + zz;
                    f32x2 m;
                    m.x = fminf(md[j].x, dd.x);
                    m.y = fminf(md[j].y, dd.y);
                    md[j] = m;
                    nu = fmaxf(nu, fmaxf(m.x, m.y));
                }
                int c = 0x7fffffff;
#pragma unroll
                for (int j = 0; j < 8; ++j) {
                    if (md[j].x == nu) c = min(c, ip[j].x);
                    if (md[j].y == nu) c = min(c, ip[j].y);
                }
                ub = nu; cand = c;
            }
            // wave reduce (DPP): max ub, then min orig idx among ties
            const float wmax = wave_fmax(ub);
            unsigned cn = (ub == wmax) ? ~(unsigned)cand : 0u;
            cn = wave_umax(cn);
            wkey = ((unsigned long long)__float_as_uint(wmax) << 32)
                 | (unsigned long long)cn;
        }
        if ((t & 63) == 0) atomicMax(&slot3[p], wkey);
        int pn = p + 1; if (pn == 3) pn = 0;
        if (t == 0) slot3[pn] = 0ull;     // reset for it+1 (readers done before barrier it-1)
        __syncthreads();
        const unsigned long long r = slot3[p];
        const int far = (int)(~(unsigned)r);
        cx = xb[3 * far + 0];
        cy = xb[3 * far + 1];
        cz = xb[3 * far + 2];
        p = pn;
    }
}

// ---------------- fallback FPS (no workspace) ----------------
__global__ __launch_bounds__(1024) void fps_kernel(const float* __restrict__ xyz,
                                                   float* __restrict__ new_xyz) {
#pragma clang fp contract(off)
    const int b = blockIdx.x;
    const int t = threadIdx.x;
    const float* xb = xyz + (size_t)b * N * 3;

    float px[16], py[16], pz[16], md[16];
#pragma unroll
    for (int k = 0; k < 16; ++k) {
        const int n = t + (k << 10);
        px[k] = xb[3 * n + 0];
        py[k] = xb[3 * n + 1];
        pz[k] = xb[3 * n + 2];
        md[k] = 1e10f;
    }
    __shared__ float rv[2][16];
    __shared__ int slot[2];
    if (t == 0) { slot[0] = 0x7fffffff; slot[1] = 0x7fffffff; }
    __syncthreads();
    int far = 0, p = 0;
    const int lane = t & 63, w = t >> 6;
    for (int it = 0; it < S; ++it) {
        const float cx = xb[3 * far + 0], cy = xb[3 * far + 1], cz = xb[3 * far + 2];
        if (t == 0) {
            float* o = new_xyz + ((size_t)b * S + it) * 3;
            o[0] = cx; o[1] = cy; o[2] = cz;
        }
        float bestv = -1.0f;
#pragma unroll
        for (int k = 0; k < 16; ++k) {
            const float dx = __fsub_rn(px[k], cx);
            const float dy = __fsub_rn(py[k], cy);
            const float dz = __fsub_rn(pz[k], cz);
            const float d  = __fadd_rn(__fadd_rn(__fmul_rn(dx, dx), __fmul_rn(dy, dy)),
                                       __fmul_rn(dz, dz));
            const float m = fminf(md[k], d);
            md[k] = m;
            bestv = fmaxf(bestv, m);
        }
        float v = bestv;
#pragma unroll
        for (int off = 32; off >= 1; off >>= 1) v = fmaxf(v, __shfl_xor(v, off));
        if (lane == 0) rv[p][w] = v;
        __syncthreads();
        float u = rv[p][lane & 15];
#pragma unroll
        for (int off = 8; off >= 1; off >>= 1) u = fmaxf(u, __shfl_xor(u, off));
        if (t == 0) slot[p ^ 1] = 0x7fffffff;
        if (bestv == u) {
            int cnd2 = 0x7fffffff;
#pragma unroll
            for (int k = 0; k < 16; ++k)
                if (md[k] == u) cnd2 = min(cnd2, t + (k << 10));
            atomicMin(&slot[p], cnd2);
        }
        __syncthreads();
        far = slot[p];
        p ^= 1;
    }
}

// ---------------- ball query + group + MLP + maxpool: one wave per query ----------------
__global__ __launch_bounds__(64) void ball_mlp_kernel(
    const float* __restrict__ xyz,
    const float* __restrict__ feat,
    const float* __restrict__ W1, const float* __restrict__ b1,
    const float* __restrict__ W2, const float* __restrict__ b2,
    const float* __restrict__ W3, const float* __restrict__ b3,
    const float* __restrict__ new_xyz,
    float* __restrict__ out_feat) {
#pragma clang fp contract(off)
    const int q = blockIdx.x;          // b*S + s
    const int b = q >> 11;             // S = 2048
    const int lane = threadIdx.x;
    const float* xb = xyz + (size_t)b * N * 3;

    const double qx = (double)new_xyz[3 * q + 0];
    const double qy = (double)new_xyz[3 * q + 1];
    const double qz = (double)new_xyz[3 * q + 2];
    const double s2 = qx * qx + qy * qy + qz * qz;
    const double R2 = 0.1 * 0.1;

    __shared__ int idxbuf[NS];
    int found = 0;
    for (int bs = 0; bs < N; bs += 64) {
        const int n = bs + lane;
        const double x = (double)xb[3 * n + 0];
        const double y = (double)xb[3 * n + 1];
        const double z = (double)xb[3 * n + 2];
        const double n2 = x * x + y * y + z * z;
        const double dt = qx * x + qy * y + qz * z;
        const double d2 = (s2 + n2) - 2.0 * dt;
        const bool ok = (d2 <= R2);
        const unsigned long long msk = __ballot(ok);
        if (ok) {
            const int pos = found + (int)__popcll(msk & ((1ull << lane) - 1ull));
            if (pos < NS) idxbuf[pos] = n;
        }
        found += (int)__popcll(msk);
        if (found >= NS) break;
    }
    __syncthreads();
    if (lane == 0) {
        const int cnt = found < NS ? found : NS;
        const int first = (cnt > 0) ? idxbuf[0] : (N - 1);
        for (int j2 = cnt; j2 < NS; ++j2) idxbuf[j2] = first;
    }
    __syncthreads();

    const int j = lane & 31;           // neighbor
    const int h = lane >> 5;           // channel half
    const int nid = idxbuf[j];
    const float* fp = feat + ((size_t)b * N + nid) * CIN;
    float fv[CIN];
#pragma unroll
    for (int k = 0; k < CIN; ++k) fv[k] = fp[k];

    float h1[32];
#pragma unroll
    for (int c = 0; c < 32; ++c) {
        float a = b1[c];
#pragma unroll
        for (int k = 0; k < CIN; ++k) a = fmaf(fv[k], W1[(k << 5) + c], a);
        h1[c] = fmaxf(a, 0.0f);
    }
    float h2[32];
#pragma unroll
    for (int c = 0; c < 32; ++c) {
        float a = b2[c];
#pragma unroll
        for (int k = 0; k < 32; ++k) a = fmaf(h1[k], W2[(k << 5) + c], a);
        h2[c] = fmaxf(a, 0.0f);
    }
    const int cbase = h << 5;
    float mx[32];
#pragma unroll
    for (int c = 0; c < 32; ++c) {
        float a = b3[cbase + c];
#pragma unroll
        for (int k = 0; k < 32; ++k) a = fmaf(h2[k], W3[(k << 6) + cbase + c], a);
        mx[c] = a;
    }
#pragma unroll
    for (int off = 1; off <= 16; off <<= 1) {
#pragma unroll
        for (int c = 0; c < 32; ++c) mx[c] = fmaxf(mx[c], __shfl_xor(mx[c], off));
    }
    if (j == 0) {
        float* o = out_feat + (size_t)q * 64 + cbase;
#pragma unroll
        for (int c = 0; c < 32; ++c) o[c] = mx[c];
    }
}

extern "C" void kernel_launch(void* const* d_in, const int* in_sizes, int n_in,
                              void* d_out, int out_size, void* d_ws, size_t ws_size,
                              hipStream_t stream) {
    (void)in_sizes; (void)n_in; (void)out_size;
    const float* xyz  = (const float*)d_in[0];
    const float* feat = (const float*)d_in[1];
    const float* W1   = (const float*)d_in[2];
    const float* b1   = (const float*)d_in[3];
    const float* W2   = (const float*)d_in[4];
    const float* b2   = (const float*)d_in[5];
    const float* W3   = (const float*)d_in[6];
    const float* b3   = (const float*)d_in[7];

    float* out      = (float*)d_out;
    float* new_xyz  = out;                          // B*S*3 floats
    float* new_feat = out + (size_t)B * S * 3;      // B*S*64 floats

    const size_t need = (size_t)4 * B * N * sizeof(float);
    if (ws_size >= need) {
        float* Xp = (float*)d_ws;
        float* Yp = Xp + (size_t)B * N;
        float* Zp = Yp + (size_t)B * N;
        int*   Ip = (int*)(Zp + (size_t)B * N);
        bucket_kernel<<<B, 1024, 0, stream>>>(xyz, Xp, Yp, Zp, Ip);
        fps_prune_kernel<<<B, 1024, 0, stream>>>(xyz, Xp, Yp, Zp, Ip, new_xyz);
    } else {
        fps_kernel<<<B, 1024, 0, stream>>>(xyz, new_xyz);
    }
    ball_mlp_kernel<<<B * S, 64, 0, stream>>>(xyz, feat, W1, b1, W2, b2, W3, b3,
                                              new_xyz, new_feat);
}

// Round 7
// 2359.292 us; speedup vs baseline: 1.2015x; 1.0010x over previous
//
#include <hip/hip_runtime.h>

#define B 8
#define N 16384
#define S 2048
#define NS 32
#define CIN 16
#define NCELL 4096   // 16^3 morton cells

typedef float f32x2 __attribute__((ext_vector_type(2)));
typedef int   i32x2 __attribute__((ext_vector_type(2)));

// ---------------- DPP wave-64 reductions (all lanes active) ----------------
template<int CTRL>
__device__ __forceinline__ float dpp_fmax(float x) {
    int t = __builtin_amdgcn_update_dpp(0, __float_as_int(x), CTRL, 0xF, 0xF, true);
    return fmaxf(x, __int_as_float(t));
}
template<int CTRL>
__device__ __forceinline__ unsigned dpp_umax(unsigned x) {
    unsigned t = (unsigned)__builtin_amdgcn_update_dpp(0, (int)x, CTRL, 0xF, 0xF, true);
    return x > t ? x : t;
}
__device__ __forceinline__ float wave_fmax(float x) {
    x = dpp_fmax<0xB1>(x);      // quad_perm xor1
    x = dpp_fmax<0x4E>(x);      // quad_perm xor2
    x = dpp_fmax<0x114>(x);     // row_shr:4
    x = dpp_fmax<0x118>(x);     // row_shr:8
    x = dpp_fmax<0x142>(x);     // row_bcast:15
    x = dpp_fmax<0x143>(x);     // row_bcast:31
    return __int_as_float(__builtin_amdgcn_readlane(__float_as_int(x), 63));
}
__device__ __forceinline__ unsigned wave_umax(unsigned x) {
    x = dpp_umax<0xB1>(x);
    x = dpp_umax<0x4E>(x);
    x = dpp_umax<0x114>(x);
    x = dpp_umax<0x118>(x);
    x = dpp_umax<0x142>(x);
    x = dpp_umax<0x143>(x);
    return (unsigned)__builtin_amdgcn_readlane((int)x, 63);
}

__device__ __forceinline__ int expand4(int v) {
    // 4-bit -> every 3rd bit (12-bit morton component)
    return (v & 1) | ((v & 2) << 2) | ((v & 4) << 4) | ((v & 8) << 6);
}

// ---------------- bucket sort: 4096-cell morton order, SoA output ----------------
__global__ __launch_bounds__(1024) void bucket_kernel(const float* __restrict__ xyz,
                                                      float* __restrict__ Xp,
                                                      float* __restrict__ Yp,
                                                      float* __restrict__ Zp,
                                                      int* __restrict__ Ip) {
    const int b = blockIdx.x;
    const int t = threadIdx.x;
    const float* xb = xyz + (size_t)b * N * 3;

    __shared__ int hist[NCELL];          // 16KB (becomes base[] after scan)
    __shared__ int run[NCELL];           // 16KB
    __shared__ int pA[1024], pB[1024];   // 8KB
    for (int i = t; i < NCELL; i += 1024) { hist[i] = 0; run[i] = 0; }
    __syncthreads();

    int cell[16];
    float xs[16], ys[16], zs[16];
#pragma unroll
    for (int k = 0; k < 16; ++k) {
        const int n = t + (k << 10);
        const float x = xb[3 * n + 0];
        const float y = xb[3 * n + 1];
        const float z = xb[3 * n + 2];
        const int cx = min(15, max(0, (int)(x * 16.0f)));
        const int cy = min(15, max(0, (int)(y * 16.0f)));
        const int cz = min(15, max(0, (int)(z * 16.0f)));
        const int c = expand4(cx) | (expand4(cy) << 1) | (expand4(cz) << 2);
        cell[k] = c; xs[k] = x; ys[k] = y; zs[k] = z;
        atomicAdd(&hist[c], 1);
    }
    __syncthreads();

    // per-thread local scan of 4 cells, then block scan of 1024 partial sums
    const int h0 = hist[4 * t + 0], h1 = hist[4 * t + 1],
              h2 = hist[4 * t + 2], h3 = hist[4 * t + 3];
    const int lsum = h0 + h1 + h2 + h3;
    pA[t] = lsum;
    __syncthreads();
    int* cur = pA; int* nxt = pB;
    for (int off = 1; off < 1024; off <<= 1) {
        nxt[t] = cur[t] + ((t >= off) ? cur[t - off] : 0);
        __syncthreads();
        int* tmp = cur; cur = nxt; nxt = tmp;
    }
    const int excl = cur[t] - lsum;      // exclusive prefix of this thread's 4 cells
    __syncthreads();                     // all hist reads done -> safe to overwrite
    hist[4 * t + 0] = excl;
    hist[4 * t + 1] = excl + h0;
    hist[4 * t + 2] = excl + h0 + h1;
    hist[4 * t + 3] = excl + h0 + h1 + h2;
    __syncthreads();

#pragma unroll
    for (int k = 0; k < 16; ++k) {
        const int c = cell[k];
        const int pos = hist[c] + atomicAdd(&run[c], 1);
        const size_t o = (size_t)b * N + pos;
        Xp[o] = xs[k]; Yp[o] = ys[k]; Zp[o] = zs[k];
        Ip[o] = t + (k << 10);
    }
}

// ---------------- FPS: bbox prune + packed-f32 update + 3-slot atomic reduce ----------------
__global__ __launch_bounds__(1024, 1) void fps_prune_kernel(const float* __restrict__ xyz,
                                                            const float* __restrict__ Xp,
                                                            const float* __restrict__ Yp,
                                                            const float* __restrict__ Zp,
                                                            const int* __restrict__ Ip,
                                                            float* __restrict__ new_xyz) {
#pragma clang fp contract(off)
    const int b = blockIdx.x;
    const int t = threadIdx.x;
    const float* xb = xyz + (size_t)b * N * 3;
    const size_t base = (size_t)b * N + ((size_t)t << 4);   // 16 consecutive sorted pts

    f32x2 px[8], py[8], pz[8], md[8];
    i32x2 ip[8];
    {
        const f32x2* X2 = (const f32x2*)(Xp + base);
        const f32x2* Y2 = (const f32x2*)(Yp + base);
        const f32x2* Z2 = (const f32x2*)(Zp + base);
        const i32x2* I2 = (const i32x2*)(Ip + base);
#pragma unroll
        for (int j = 0; j < 8; ++j) {
            px[j] = X2[j]; py[j] = Y2[j]; pz[j] = Z2[j]; ip[j] = I2[j];
            md[j] = (f32x2){1e10f, 1e10f};
        }
    }

    // per-thread bbox (tight: points are Morton-adjacent)
    float lox = px[0].x, hix = px[0].x, loy = py[0].x, hiy = py[0].x,
          loz = pz[0].x, hiz = pz[0].x;
#pragma unroll
    for (int j = 0; j < 8; ++j) {
        lox = fminf(lox, fminf(px[j].x, px[j].y)); hix = fmaxf(hix, fmaxf(px[j].x, px[j].y));
        loy = fminf(loy, fminf(py[j].x, py[j].y)); hiy = fmaxf(hiy, fmaxf(py[j].x, py[j].y));
        loz = fminf(loz, fminf(pz[j].x, pz[j].y)); hiz = fmaxf(hiz, fmaxf(pz[j].x, pz[j].y));
    }

    __shared__ unsigned long long slot3[3];
    if (t == 0) { slot3[0] = 0ull; slot3[1] = 0ull; slot3[2] = 0ull; }
    __syncthreads();

    int p = 0;
    float ub = 1e10f;
    int cand = ip[0].x;
    unsigned long long wkey = 0ull;
    float cx = xb[0], cy = xb[1], cz = xb[2];   // initial centroid = original point 0

    for (int it = 0; it < S; ++it) {
        if (t == 0) {
            float* o = new_xyz + ((size_t)b * S + it) * 3;
            o[0] = cx; o[1] = cy; o[2] = cz;
        }
        // exact conservative skip: lb*(1-2e-5) > ub  =>  d_fp32 > md for all 16 pts
        const float ddx = fmaxf(0.0f, fmaxf(lox - cx, cx - hix));
        const float ddy = fmaxf(0.0f, fmaxf(loy - cy, cy - hiy));
        const float ddz = fmaxf(0.0f, fmaxf(loz - cz, cz - hiz));
        const float lb = (ddx * ddx + ddy * ddy) + ddz * ddz;
        const bool upd = !(lb * 0.99998f > ub);

        if (__any(upd)) {                 // wave-uniform branch
            if (upd) {
                asm volatile("" : "+v"(px[0]), "+v"(px[1]), "+v"(px[2]), "+v"(px[3]),
                                  "+v"(px[4]), "+v"(px[5]), "+v"(px[6]), "+v"(px[7]));
                asm volatile("" : "+v"(py[0]), "+v"(py[1]), "+v"(py[2]), "+v"(py[3]),
                                  "+v"(py[4]), "+v"(py[5]), "+v"(py[6]), "+v"(py[7]));
                asm volatile("" : "+v"(pz[0]), "+v"(pz[1]), "+v"(pz[2]), "+v"(pz[3]),
                                  "+v"(pz[4]), "+v"(pz[5]), "+v"(pz[6]), "+v"(pz[7]));
                asm volatile("" : "+v"(ip[0]), "+v"(ip[1]), "+v"(ip[2]), "+v"(ip[3]),
                                  "+v"(ip[4]), "+v"(ip[5]), "+v"(ip[6]), "+v"(ip[7]));
                const f32x2 c2x = {cx, cx}, c2y = {cy, cy}, c2z = {cz, cz};
                f32x2 nu2 = {0.0f, 0.0f};
#pragma unroll
                for (int j = 0; j < 8; ++j) {
                    // identical rounding order to scalar version; v_pk_* ops
                    const f32x2 dx = px[j] - c2x;
                    const f32x2 dy = py[j] - c2y;
                    const f32x2 dz = pz[j] - c2z;
                    const f32x2 dd = (dx * dx + dy * dy) + dz * dz;
                    const f32x2 m = __builtin_elementwise_min(md[j], dd);
                    md[j] = m;
                    nu2 = __builtin_elementwise_max(nu2, m);
                }
                const float nu = fmaxf(nu2.x, nu2.y);   // max exact-assoc => same as seq chain
                int c = 0x7fffffff;
#pragma unroll
                for (int j = 0; j < 8; ++j) {
                    if (md[j].x == nu) c = min(c, ip[j].x);
                    if (md[j].y == nu) c = min(c, ip[j].y);
                }
                ub = nu; cand = c;
            }
            // wave reduce (DPP): max ub, then min orig idx among ties
            const float wmax = wave_fmax(ub);
            unsigned cn = (ub == wmax) ? ~(unsigned)cand : 0u;
            cn = wave_umax(cn);
            wkey = ((unsigned long long)__float_as_uint(wmax) << 32)
                 | (unsigned long long)cn;
        }
        if ((t & 63) == 0) atomicMax(&slot3[p], wkey);
        int pn = p + 1; if (pn == 3) pn = 0;
        if (t == 0) slot3[pn] = 0ull;     // reset for it+1 (readers done before barrier it-1)
        __syncthreads();
        const unsigned long long r = slot3[p];
        // uniform index -> SGPR -> scalar loads (s_load), shortens dependent chain
        const int fu = __builtin_amdgcn_readfirstlane((int)(~(unsigned)r));
        cx = xb[3 * fu + 0];
        cy = xb[3 * fu + 1];
        cz = xb[3 * fu + 2];
        p = pn;
    }
}

// ---------------- fallback FPS (no workspace) ----------------
__global__ __launch_bounds__(1024) void fps_kernel(const float* __restrict__ xyz,
                                                   float* __restrict__ new_xyz) {
#pragma clang fp contract(off)
    const int b = blockIdx.x;
    const int t = threadIdx.x;
    const float* xb = xyz + (size_t)b * N * 3;

    float px[16], py[16], pz[16], md[16];
#pragma unroll
    for (int k = 0; k < 16; ++k) {
        const int n = t + (k << 10);
        px[k] = xb[3 * n + 0];
        py[k] = xb[3 * n + 1];
        pz[k] = xb[3 * n + 2];
        md[k] = 1e10f;
    }
    __shared__ float rv[2][16];
    __shared__ int slot[2];
    if (t == 0) { slot[0] = 0x7fffffff; slot[1] = 0x7fffffff; }
    __syncthreads();
    int far = 0, p = 0;
    const int lane = t & 63, w = t >> 6;
    for (int it = 0; it < S; ++it) {
        const float cx = xb[3 * far + 0], cy = xb[3 * far + 1], cz = xb[3 * far + 2];
        if (t == 0) {
            float* o = new_xyz + ((size_t)b * S + it) * 3;
            o[0] = cx; o[1] = cy; o[2] = cz;
        }
        float bestv = -1.0f;
#pragma unroll
        for (int k = 0; k < 16; ++k) {
            const float dx = __fsub_rn(px[k], cx);
            const float dy = __fsub_rn(py[k], cy);
            const float dz = __fsub_rn(pz[k], cz);
            const float d  = __fadd_rn(__fadd_rn(__fmul_rn(dx, dx), __fmul_rn(dy, dy)),
                                       __fmul_rn(dz, dz));
            const float m = fminf(md[k], d);
            md[k] = m;
            bestv = fmaxf(bestv, m);
        }
        float v = bestv;
#pragma unroll
        for (int off = 32; off >= 1; off >>= 1) v = fmaxf(v, __shfl_xor(v, off));
        if (lane == 0) rv[p][w] = v;
        __syncthreads();
        float u = rv[p][lane & 15];
#pragma unroll
        for (int off = 8; off >= 1; off >>= 1) u = fmaxf(u, __shfl_xor(u, off));
        if (t == 0) slot[p ^ 1] = 0x7fffffff;
        if (bestv == u) {
            int cnd2 = 0x7fffffff;
#pragma unroll
            for (int k = 0; k < 16; ++k)
                if (md[k] == u) cnd2 = min(cnd2, t + (k << 10));
            atomicMin(&slot[p], cnd2);
        }
        __syncthreads();
        far = slot[p];
        p ^= 1;
    }
}

// ---------------- ball query + group + MLP + maxpool: one wave per query ----------------
__global__ __launch_bounds__(64) void ball_mlp_kernel(
    const float* __restrict__ xyz,
    const float* __restrict__ feat,
    const float* __restrict__ W1, const float* __restrict__ b1,
    const float* __restrict__ W2, const float* __restrict__ b2,
    const float* __restrict__ W3, const float* __restrict__ b3,
    const float* __restrict__ new_xyz,
    float* __restrict__ out_feat) {
#pragma clang fp contract(off)
    const int q = blockIdx.x;          // b*S + s
    const int b = q >> 11;             // S = 2048
    const int lane = threadIdx.x;
    const float* xb = xyz + (size_t)b * N * 3;

    const double qx = (double)new_xyz[3 * q + 0];
    const double qy = (double)new_xyz[3 * q + 1];
    const double qz = (double)new_xyz[3 * q + 2];
    const double s2 = qx * qx + qy * qy + qz * qz;
    const double R2 = 0.1 * 0.1;

    __shared__ int idxbuf[NS];
    int found = 0;
    for (int bs = 0; bs < N; bs += 64) {
        const int n = bs + lane;
        const double x = (double)xb[3 * n + 0];
        const double y = (double)xb[3 * n + 1];
        const double z = (double)xb[3 * n + 2];
        const double n2 = x * x + y * y + z * z;
        const double dt = qx * x + qy * y + qz * z;
        const double d2 = (s2 + n2) - 2.0 * dt;
        const bool ok = (d2 <= R2);
        const unsigned long long msk = __ballot(ok);
        if (ok) {
            const int pos = found + (int)__popcll(msk & ((1ull << lane) - 1ull));
            if (pos < NS) idxbuf[pos] = n;
        }
        found += (int)__popcll(msk);
        if (found >= NS) break;
    }
    __syncthreads();
    if (lane == 0) {
        const int cnt = found < NS ? found : NS;
        const int first = (cnt > 0) ? idxbuf[0] : (N - 1);
        for (int j2 = cnt; j2 < NS; ++j2) idxbuf[j2] = first;
    }
    __syncthreads();

    const int j = lane & 31;           // neighbor
    const int h = lane >> 5;           // channel half
    const int nid = idxbuf[j];
    const float* fp = feat + ((size_t)b * N + nid) * CIN;
    float fv[CIN];
#pragma unroll
    for (int k = 0; k < CIN; ++k) fv[k] = fp[k];

    float h1[32];
#pragma unroll
    for (int c = 0; c < 32; ++c) {
        float a = b1[c];
#pragma unroll
        for (int k = 0; k < CIN; ++k) a = fmaf(fv[k], W1[(k << 5) + c], a);
        h1[c] = fmaxf(a, 0.0f);
    }
    float h2[32];
#pragma unroll
    for (int c = 0; c < 32; ++c) {
        float a = b2[c];
#pragma unroll
        for (int k = 0; k < 32; ++k) a = fmaf(h1[k], W2[(k << 5) + c], a);
        h2[c] = fmaxf(a, 0.0f);
    }
    const int cbase = h << 5;
    float mx[32];
#pragma unroll
    for (int c = 0; c < 32; ++c) {
        float a = b3[cbase + c];
#pragma unroll
        for (int k = 0; k < 32; ++k) a = fmaf(h2[k], W3[(k << 6) + cbase + c], a);
        mx[c] = a;
    }
#pragma unroll
    for (int off = 1; off <= 16; off <<= 1) {
#pragma unroll
        for (int c = 0; c < 32; ++c) mx[c] = fmaxf(mx[c], __shfl_xor(mx[c], off));
    }
    if (j == 0) {
        float* o = out_feat + (size_t)q * 64 + cbase;
#pragma unroll
        for (int c = 0; c < 32; ++c) o[c] = mx[c];
    }
}

extern "C" void kernel_launch(void* const* d_in, const int* in_sizes, int n_in,
                              void* d_out, int out_size, void* d_ws, size_t ws_size,
                              hipStream_t stream) {
    (void)in_sizes; (void)n_in; (void)out_size;
    const float* xyz  = (const float*)d_in[0];
    const float* feat = (const float*)d_in[1];
    const float* W1   = (const float*)d_in[2];
    const float* b1   = (const float*)d_in[3];
    const float* W2   = (const float*)d_in[4];
    const float* b2   = (const float*)d_in[5];
    const float* W3   = (const float*)d_in[6];
    const float* b3   = (const float*)d_in[7];

    float* out      = (float*)d_out;
    float* new_xyz  = out;                          // B*S*3 floats
    float* new_feat = out + (size_t)B * S * 3;      // B*S*64 floats

    const size_t need = (size_t)4 * B * N * sizeof(float);
    if (ws_size >= need) {
        float* Xp = (float*)d_ws;
        float* Yp = Xp + (size_t)B * N;
        float* Zp = Yp + (size_t)B * N;
        int*   Ip = (int*)(Zp + (size_t)B * N);
        bucket_kernel<<<B, 1024, 0, stream>>>(xyz, Xp, Yp, Zp, Ip);
        fps_prune_kernel<<<B, 1024, 0, stream>>>(xyz, Xp, Yp, Zp, Ip, new_xyz);
    } else {
        fps_kernel<<<B, 1024, 0, stream>>>(xyz, new_xyz);
    }
    ball_mlp_kernel<<<B * S, 64, 0, stream>>>(xyz, feat, W1, b1, W2, b2, W3, b3,
                                              new_xyz, new_feat);
}